// Round 8
// baseline (132.876 us; speedup 1.0000x reference)
//
#include <hip/hip_runtime.h>
#include <hip/hip_fp16.h>
#include <math.h>

#define DET 512
#define NA 180
#define NTILES 1024                   // 32 x 32 tiles of 16x16 pixels
#define TANG_FLOATS (NTILES * NA * 4) // 2.95 MB
#define CHUNK 18
#define WWIN 24
#define NCH 5                         // chunks per half (90 angles)

typedef _Float16 half2_t __attribute__((ext_vector_type(2)));

// ws layout (floats):
//  [0, TANG_FLOATS)  : tang float4 per (tile,angle): {bias=255.5-w0, C, S, w0 int bits}
//  then xsT2         : uint4[NA*DET*2] tap-pair-packed sinogram (2.95 MB):
//                      uint4 (a,d,g) = { half2(s_b[d], s_b[d+1]) : b = 4g..4g+3 }

// ---------------- fused prep + filter ----------------
// blocks [0, 2*NA): filter (angle = blk>>1, batch-half z = blk&1, 4 batches)
// blocks [2*NA, 2*NA+720): prep of tang
__global__ __launch_bounds__(256) void prep_filter_kernel(const float* __restrict__ x,
                                                          float4* __restrict__ tang,
                                                          uint4* __restrict__ xsT2) {
    const int t = threadIdx.x;
    if (blockIdx.x >= 2 * NA) {
        int idx = (blockIdx.x - 2 * NA) * 256 + t;
        if (idx < NTILES * NA) {
            int tile = idx / NA;
            int a = idx - tile * NA;
            float th = (float)a * 0.017453292519943295f;
            float C = 255.5f * cosf(th);
            float S = 255.5f * sinf(th);
            int x0 = (tile & 31) << 4, y0 = (tile >> 5) << 4;
            float xga = (float)(2 * x0 - 511)        * (1.0f / 511.0f);
            float xgb = (float)(2 * (x0 + 15) - 511) * (1.0f / 511.0f);
            float yga = (float)(2 * y0 - 511)        * (1.0f / 511.0f);
            float ygb = (float)(2 * (y0 + 15) - 511) * (1.0f / 511.0f);
            // min over tile corners of yv = 255.5 + xg*C - yg*S (linear in xg,yg)
            float mn = 255.5f + fminf(xga * C, xgb * C) + fminf(-yga * S, -ygb * S);
            int w0 = (int)floorf(mn) - 1;     // -1 slack for fma rounding differences
            tang[idx] = make_float4(255.5f - (float)w0, C, S, __int_as_float(w0));
        }
        return;
    }

    // ---- filter: one wave = full 512-tap conv of one batch-column ----
    __shared__ float xcols[4][DET];   // 8 KB
    __shared__ float g2s[1024];       // 4 KB  g2s[i] = g(|i-512|)
    __shared__ float part[4][DET];    // 8 KB

    const int a = blockIdx.x >> 1;
    const int z = blockIdx.x & 1;

    for (int i = t; i < 1024; i += 256) {
        int k = i - 512; if (k < 0) k = -k;
        float g = 0.0f;
        if (k == 0)      g = 0.5f;
        else if (k & 1)  { float fk = (float)k; g = -0.20264236728467558f / (fk * fk); }
        g2s[i] = g;
    }
    for (int i = t; i < 4 * DET; i += 256) {
        int b = i >> 9, j = i & 511;
        xcols[b][j] = x[((4 * z + b) * DET + j) * NA + a];
    }
    __syncthreads();

    const int w  = t >> 6, l = t & 63;
    const int d0 = l << 3;

    float acc[8];
#pragma unroll
    for (int r = 0; r < 8; ++r) acc[r] = 0.0f;

    float W[16];
#pragma unroll
    for (int q = 0; q < 4; ++q)
        *(float4*)(W + 4 * q) = *(const float4*)(g2s + 504 + d0 + 4 * q);
    float xv[8];
    *(float4*)(xv)     = *(const float4*)(&xcols[w][0]);
    *(float4*)(xv + 4) = *(const float4*)(&xcols[w][4]);

    for (int j0 = 0; j0 < 512; j0 += 8) {
        float nxv[8], nW[8];
        const bool more = (j0 < 504);
        if (more) {
            *(float4*)(nxv)     = *(const float4*)(&xcols[w][j0 + 8]);
            *(float4*)(nxv + 4) = *(const float4*)(&xcols[w][j0 + 12]);
            *(float4*)(nW)      = *(const float4*)(g2s + 496 + d0 - j0);
            *(float4*)(nW + 4)  = *(const float4*)(g2s + 500 + d0 - j0);
        }
#pragma unroll
        for (int jj = 0; jj < 8; ++jj)
#pragma unroll
            for (int r = 0; r < 8; ++r)
                acc[r] = fmaf(xv[jj], W[8 + r - jj], acc[r]);
        if (more) {
#pragma unroll
            for (int i = 7; i >= 0; --i) W[i + 8] = W[i];
#pragma unroll
            for (int i = 0; i < 8; ++i) { W[i] = nW[i]; xv[i] = nxv[i]; }
        }
    }

    *(float4*)(&part[w][d0])     = *(const float4*)(acc);
    *(float4*)(&part[w][d0 + 4]) = *(const float4*)(acc + 4);
    __syncthreads();

    // tap-pair pack: word b = half2(part[b][i], part[b][i+1]); d=511 pairs with 0
    for (int i = t; i < DET; i += 256) {
        uint4 pk;
        unsigned* pkw = &pk.x;
#pragma unroll
        for (int b = 0; b < 4; ++b) {
            float v0 = part[b][i];
            float v1 = (i < DET - 1) ? part[b][i + 1] : 0.0f;
            __half2 h = __halves2half2(__float2half_rn(v0), __float2half_rn(v1));
            pkw[b] = *(unsigned*)&h;
        }
        xsT2[((size_t)a * DET + i) * 2 + z] = pk;
    }
}

// ---------------- backprojection: angle-split halves, 8 blocks/CU ----------------
// grid 2048: tile = bx & 1023, half = bx >> 10 (angles [90h, 90h+90)).
// 1 thread = 1 pixel x 8 batches; per pixel-angle: addr math once, 2 ds_read_b128, 8 dot2.
// Halves accumulate into d_out via atomicAdd (d_out zeroed by memset; mask/scale pre-applied).
__global__ __launch_bounds__(256, 8) void backproj_kernel(const float4* __restrict__ tang,
                                                          const uint4* __restrict__ xs,
                                                          float* __restrict__ out) {
    __shared__ uint4 win[2][CHUNK][WWIN];   // 13.8 KB -> 8 blocks/CU

    const int tile = blockIdx.x & 1023;
    const int abase = (blockIdx.x >> 10) * 90;
    const int x0 = (tile & 31) << 4, y0 = (tile >> 5) << 4;
    const int t = threadIdx.x;
    const int px = t & 15, py = t >> 4;
    const float xg = (float)(2 * (x0 + px) - 511) * (1.0f / 511.0f);
    const float yg = (float)(2 * (y0 + py) - 511) * (1.0f / 511.0f);

    float acc[8];
#pragma unroll
    for (int j = 0; j < 8; ++j) acc[j] = 0.0f;

    const float4* ta = tang + (size_t)tile * NA;

    for (int c = 0; c < NCH; ++c) {
        __syncthreads();   // previous chunk's readers done
        // stage CHUNK windows: CHUNK*WWIN*2 uint4s, coalesced (off,gg fastest)
        for (int i = t; i < CHUNK * WWIN * 2; i += 256) {
            int ci  = i / (WWIN * 2);
            int r   = i - ci * (WWIN * 2);
            int off = r >> 1, gg = r & 1;
            int a   = abase + c * CHUNK + ci;
            int d   = __float_as_int(ta[a].w) + off;
            uint4 v = make_uint4(0u, 0u, 0u, 0u);
            if ((unsigned)d < 512u)
                v = xs[((size_t)a * DET + d) * 2 + gg];
            win[gg][ci][off] = v;
        }
        __syncthreads();

#pragma unroll 6
        for (int ci = 0; ci < CHUNK; ++ci) {
            float4 A = ta[abase + c * CHUNK + ci];     // uniform -> s_load_dwordx4
            float yv = fmaf(xg, A.y, A.x) - yg * A.z;  // window-relative, >= 1
            float fi = floorf(yv);
            int  off = (int)fi;
            float wgt = yv - fi;
            auto pkw = __builtin_amdgcn_cvt_pkrtz(1.0f - wgt, wgt);  // v_cvt_pkrtz_f16_f32
            half2_t wv = *(half2_t*)&pkw;
            uint4 u0 = win[0][ci][off];                // ds_read_b128
            uint4 u1 = win[1][ci][off];                // ds_read_b128, +imm offset
            acc[0] = __builtin_amdgcn_fdot2(*(half2_t*)&u0.x, wv, acc[0], false);
            acc[1] = __builtin_amdgcn_fdot2(*(half2_t*)&u0.y, wv, acc[1], false);
            acc[2] = __builtin_amdgcn_fdot2(*(half2_t*)&u0.z, wv, acc[2], false);
            acc[3] = __builtin_amdgcn_fdot2(*(half2_t*)&u0.w, wv, acc[3], false);
            acc[4] = __builtin_amdgcn_fdot2(*(half2_t*)&u1.x, wv, acc[4], false);
            acc[5] = __builtin_amdgcn_fdot2(*(half2_t*)&u1.y, wv, acc[5], false);
            acc[6] = __builtin_amdgcn_fdot2(*(half2_t*)&u1.z, wv, acc[6], false);
            acc[7] = __builtin_amdgcn_fdot2(*(half2_t*)&u1.w, wv, acc[7], false);
        }
    }

    const float r2 = xg * xg + yg * yg;
    const float m  = (r2 <= 1.0f) ? 0.008726646259971648f : 0.0f;  // pi/360 masked
    const size_t pbase = ((size_t)(y0 + py) << 9) + (size_t)(x0 + px);
#pragma unroll
    for (int j = 0; j < 8; ++j)
        atomicAdd(&out[((size_t)j << 18) + pbase], acc[j] * m);
}

extern "C" void kernel_launch(void* const* d_in, const int* in_sizes, int n_in,
                              void* d_out, int out_size, void* d_ws, size_t ws_size,
                              hipStream_t stream) {
    const float* x = (const float*)d_in[0];
    float* out = (float*)d_out;
    float* ws  = (float*)d_ws;

    float4* tang = (float4*)ws;
    uint4*  xsT2 = (uint4*)(ws + TANG_FLOATS);

    hipMemsetAsync(d_out, 0, (size_t)out_size * sizeof(float), stream);
    const int prep_blocks = (NTILES * NA + 255) / 256;   // 720
    prep_filter_kernel<<<2 * NA + prep_blocks, 256, 0, stream>>>(x, tang, xsT2);
    backproj_kernel<<<2 * NTILES, 256, 0, stream>>>(tang, xsT2, out);
}

// Round 9
// 128.916 us; speedup vs baseline: 1.0307x; 1.0307x over previous
//
#include <hip/hip_runtime.h>
#include <hip/hip_fp16.h>
#include <math.h>

#define DET 512
#define NA 180
#define NTILES 1024                   // 32 x 32 tiles of 16x16 pixels
#define TANG_FLOATS (NTILES * NA * 4) // 2.95 MB
#define CHUNK 36
#define WWIN 24
#define NITEM (CHUNK * WWIN * 2)      // 1728 uint4 per chunk
#define NPF 7                         // ceil(1728/256)

typedef _Float16 half2_t __attribute__((ext_vector_type(2)));

// ws layout (floats):
//  [0, TANG_FLOATS)  : tang float4 per (tile,angle): {bias=255.5-w0, C, S, w0 int bits}
//  then xsT2         : uint4[NA*DET*2] tap-pair-packed sinogram (2.95 MB):
//                      uint4 (a,d,g) = { half2(s_b[d], s_b[d+1]) : b = 4g..4g+3 }

// ---------------- fused prep + filter ----------------
// blocks [0, 2*NA): filter (angle = blk>>1, batch-half z = blk&1, 4 batches)
// blocks [2*NA, 2*NA+720): prep of tang
__global__ __launch_bounds__(256) void prep_filter_kernel(const float* __restrict__ x,
                                                          float4* __restrict__ tang,
                                                          uint4* __restrict__ xsT2) {
    const int t = threadIdx.x;
    if (blockIdx.x >= 2 * NA) {
        int idx = (blockIdx.x - 2 * NA) * 256 + t;
        if (idx < NTILES * NA) {
            int tile = idx / NA;
            int a = idx - tile * NA;
            float th = (float)a * 0.017453292519943295f;
            float C = 255.5f * cosf(th);
            float S = 255.5f * sinf(th);
            int x0 = (tile & 31) << 4, y0 = (tile >> 5) << 4;
            float xga = (float)(2 * x0 - 511)        * (1.0f / 511.0f);
            float xgb = (float)(2 * (x0 + 15) - 511) * (1.0f / 511.0f);
            float yga = (float)(2 * y0 - 511)        * (1.0f / 511.0f);
            float ygb = (float)(2 * (y0 + 15) - 511) * (1.0f / 511.0f);
            // min over tile corners of yv = 255.5 + xg*C - yg*S (linear in xg,yg)
            float mn = 255.5f + fminf(xga * C, xgb * C) + fminf(-yga * S, -ygb * S);
            int w0 = (int)floorf(mn) - 1;     // -1 slack for fma rounding differences
            tang[idx] = make_float4(255.5f - (float)w0, C, S, __int_as_float(w0));
        }
        return;
    }

    // ---- filter: one wave = full 512-tap conv of one batch-column ----
    __shared__ float xcols[4][DET];   // 8 KB
    __shared__ float g2s[1024];       // 4 KB  g2s[i] = g(|i-512|)
    __shared__ float part[4][DET];    // 8 KB

    const int a = blockIdx.x >> 1;
    const int z = blockIdx.x & 1;

    for (int i = t; i < 1024; i += 256) {
        int k = i - 512; if (k < 0) k = -k;
        float g = 0.0f;
        if (k == 0)      g = 0.5f;
        else if (k & 1)  { float fk = (float)k; g = -0.20264236728467558f / (fk * fk); }
        g2s[i] = g;
    }
    for (int i = t; i < 4 * DET; i += 256) {
        int b = i >> 9, j = i & 511;
        xcols[b][j] = x[((4 * z + b) * DET + j) * NA + a];
    }
    __syncthreads();

    const int w  = t >> 6, l = t & 63;
    const int d0 = l << 3;

    float acc[8];
#pragma unroll
    for (int r = 0; r < 8; ++r) acc[r] = 0.0f;

    float W[16];
#pragma unroll
    for (int q = 0; q < 4; ++q)
        *(float4*)(W + 4 * q) = *(const float4*)(g2s + 504 + d0 + 4 * q);
    float xv[8];
    *(float4*)(xv)     = *(const float4*)(&xcols[w][0]);
    *(float4*)(xv + 4) = *(const float4*)(&xcols[w][4]);

    for (int j0 = 0; j0 < 512; j0 += 8) {
        float nxv[8], nW[8];
        const bool more = (j0 < 504);
        if (more) {
            *(float4*)(nxv)     = *(const float4*)(&xcols[w][j0 + 8]);
            *(float4*)(nxv + 4) = *(const float4*)(&xcols[w][j0 + 12]);
            *(float4*)(nW)      = *(const float4*)(g2s + 496 + d0 - j0);
            *(float4*)(nW + 4)  = *(const float4*)(g2s + 500 + d0 - j0);
        }
#pragma unroll
        for (int jj = 0; jj < 8; ++jj)
#pragma unroll
            for (int r = 0; r < 8; ++r)
                acc[r] = fmaf(xv[jj], W[8 + r - jj], acc[r]);
        if (more) {
#pragma unroll
            for (int i = 7; i >= 0; --i) W[i + 8] = W[i];
#pragma unroll
            for (int i = 0; i < 8; ++i) { W[i] = nW[i]; xv[i] = nxv[i]; }
        }
    }

    *(float4*)(&part[w][d0])     = *(const float4*)(acc);
    *(float4*)(&part[w][d0 + 4]) = *(const float4*)(acc + 4);
    __syncthreads();

    // tap-pair pack: word b = half2(part[b][i], part[b][i+1]); d=511 pairs with 0
    for (int i = t; i < DET; i += 256) {
        uint4 pk;
        unsigned* pkw = &pk.x;
#pragma unroll
        for (int b = 0; b < 4; ++b) {
            float v0 = part[b][i];
            float v1 = (i < DET - 1) ? part[b][i + 1] : 0.0f;
            __half2 h = __halves2half2(__float2half_rn(v0), __float2half_rn(v1));
            pkw[b] = *(unsigned*)&h;
        }
        xsT2[((size_t)a * DET + i) * 2 + z] = pk;
    }
}

// ---------------- backprojection: register-prefetch pipelined staging ----------------
// 1024 blocks (16x16 tile each), 1 thread = 1 pixel x 8 batches.
// Chunk c+1's global loads are issued right after chunk c's LDS is populated and
// consumed only at the next write phase -> L2 latency hidden behind 36 angles of compute.
__global__ __launch_bounds__(256, 4) void backproj_kernel(const float4* __restrict__ tang,
                                                          const uint4* __restrict__ xs,
                                                          float* __restrict__ out) {
    __shared__ uint4 win[2][CHUNK][WWIN];   // 27.6 KB -> 4 blocks/CU

    const int tile = blockIdx.x;
    const int x0 = (tile & 31) << 4, y0 = (tile >> 5) << 4;
    const int t = threadIdx.x;
    const int px = t & 15, py = t >> 4;
    const float xg = (float)(2 * (x0 + px) - 511) * (1.0f / 511.0f);
    const float yg = (float)(2 * (y0 + py) - 511) * (1.0f / 511.0f);

    float acc[8];
#pragma unroll
    for (int j = 0; j < 8; ++j) acc[j] = 0.0f;

    const float4* ta = tang + (size_t)tile * NA;

    uint4 p[NPF];

    // prefetch chunk 0
#pragma unroll
    for (int k = 0; k < NPF; ++k) {
        int i = t + 256 * k;
        p[k] = make_uint4(0u, 0u, 0u, 0u);
        if (i < NITEM) {
            int ci  = i / (WWIN * 2);
            int r   = i - ci * (WWIN * 2);
            int off = r >> 1, gg = r & 1;
            int a   = ci;
            int d   = __float_as_int(ta[a].w) + off;
            if ((unsigned)d < 512u)
                p[k] = xs[((size_t)a * DET + d) * 2 + gg];
        }
    }

    for (int c = 0; c < NA / CHUNK; ++c) {
        __syncthreads();   // previous chunk's readers done
        // write prefetched registers to LDS (compiler waits vmcnt here)
#pragma unroll
        for (int k = 0; k < NPF; ++k) {
            int i = t + 256 * k;
            if (i < NITEM) {
                int ci  = i / (WWIN * 2);
                int r   = i - ci * (WWIN * 2);
                int off = r >> 1, gg = r & 1;
                win[gg][ci][off] = p[k];
            }
        }
        __syncthreads();

        // issue next chunk's loads (no wait until next write phase)
        if (c < NA / CHUNK - 1) {
#pragma unroll
            for (int k = 0; k < NPF; ++k) {
                int i = t + 256 * k;
                p[k] = make_uint4(0u, 0u, 0u, 0u);
                if (i < NITEM) {
                    int ci  = i / (WWIN * 2);
                    int r   = i - ci * (WWIN * 2);
                    int off = r >> 1, gg = r & 1;
                    int a   = (c + 1) * CHUNK + ci;
                    int d   = __float_as_int(ta[a].w) + off;
                    if ((unsigned)d < 512u)
                        p[k] = xs[((size_t)a * DET + d) * 2 + gg];
                }
            }
        }

#pragma unroll 6
        for (int ci = 0; ci < CHUNK; ++ci) {
            float4 A = ta[c * CHUNK + ci];             // uniform -> s_load_dwordx4
            float yv = fmaf(xg, A.y, A.x) - yg * A.z;  // window-relative, >= 1
            float fi = floorf(yv);
            int  off = (int)fi;
            float wgt = yv - fi;
            auto pkw = __builtin_amdgcn_cvt_pkrtz(1.0f - wgt, wgt);  // v_cvt_pkrtz_f16_f32
            half2_t wv = *(half2_t*)&pkw;
            uint4 u0 = win[0][ci][off];                // ds_read_b128
            uint4 u1 = win[1][ci][off];                // ds_read_b128, +imm offset
            acc[0] = __builtin_amdgcn_fdot2(*(half2_t*)&u0.x, wv, acc[0], false);
            acc[1] = __builtin_amdgcn_fdot2(*(half2_t*)&u0.y, wv, acc[1], false);
            acc[2] = __builtin_amdgcn_fdot2(*(half2_t*)&u0.z, wv, acc[2], false);
            acc[3] = __builtin_amdgcn_fdot2(*(half2_t*)&u0.w, wv, acc[3], false);
            acc[4] = __builtin_amdgcn_fdot2(*(half2_t*)&u1.x, wv, acc[4], false);
            acc[5] = __builtin_amdgcn_fdot2(*(half2_t*)&u1.y, wv, acc[5], false);
            acc[6] = __builtin_amdgcn_fdot2(*(half2_t*)&u1.z, wv, acc[6], false);
            acc[7] = __builtin_amdgcn_fdot2(*(half2_t*)&u1.w, wv, acc[7], false);
        }
    }

    const float r2 = xg * xg + yg * yg;
    const float m  = (r2 <= 1.0f) ? 0.008726646259971648f : 0.0f;  // pi/360 masked
    const size_t pbase = ((size_t)(y0 + py) << 9) + (size_t)(x0 + px);
#pragma unroll
    for (int j = 0; j < 8; ++j)
        out[((size_t)j << 18) + pbase] = acc[j] * m;
}

extern "C" void kernel_launch(void* const* d_in, const int* in_sizes, int n_in,
                              void* d_out, int out_size, void* d_ws, size_t ws_size,
                              hipStream_t stream) {
    const float* x = (const float*)d_in[0];
    float* out = (float*)d_out;
    float* ws  = (float*)d_ws;

    float4* tang = (float4*)ws;
    uint4*  xsT2 = (uint4*)(ws + TANG_FLOATS);

    const int prep_blocks = (NTILES * NA + 255) / 256;   // 720
    prep_filter_kernel<<<2 * NA + prep_blocks, 256, 0, stream>>>(x, tang, xsT2);
    backproj_kernel<<<NTILES, 256, 0, stream>>>(tang, xsT2, out);
}